// Round 8
// baseline (174.946 us; speedup 1.0000x reference)
//
#include <hip/hip_runtime.h>
#include <stdint.h>

#define NN 2048
#define DD 256
#define LL 4
#define DIN 128
#define DOUT 64
#define EE 65536
#define BM 4          // rows per block; NN/BM = 512 blocks -> 2 blocks/CU

// ---------------------------------------------------------------------------
// Established (prev session + rounds 0-7):
// * f32 in/out; attention contributes exactly zero (verified bit-identical).
// * Surviving computation: h0 = x@Win + b_in + z[clip(deg,0,63)];
//   per layer: xp = h + bo[l]; h = LN2(xp)@Wff[l] + bff[l] + xp;
//   out = h@Wout + b_out.
// * R3: deep W prefetch fixed L2-latency wall (63->42us, VGPR 44, no spill).
// * R4: readlane FAILED. R5 (best, 40.3us): halving DS broadcasts -5%.
// * R6/R7: SPILLED (WRITE_SIZE 25/38MB, scratch) - float4 prefetch arrays
//   overflowed the launch_bounds VGPR cap; structures never tested clean.
// * R8 (this): BM=4 so shnT[k] = ONE float4 (4 rows): 1 uniform b128
//   broadcast per k feeds 16 FMAs (4 cols/lane). FF broadcasts/block/layer
//   2048(R3)->256. 8 single-stage wave-owned partial planes (32KB), b128
//   writes, 3 barriers/layer. Grid 512 = 2 blocks/CU (independent barrier
//   domains fill each other's waits). VGPR audited ~105 < 128 cap
//   (launch_bounds(512,4)); W dbuf depth 4. Spill signature to check:
//   WRITE_SIZE ~0.5MB, VGPR ~100-110.
// ---------------------------------------------------------------------------

__global__ __launch_bounds__(1024) void k_deg(const int* __restrict__ ei, int* __restrict__ deg) {
    __shared__ int hist[NN];
    for (int i = threadIdx.x; i < NN; i += 1024) hist[i] = 0;
    __syncthreads();
    const int4* p = (const int4*)(ei + blockIdx.x * (EE / 8));
    for (int i = threadIdx.x; i < (EE / 8) / 4; i += 1024) {
        int4 v = p[i];
        if ((unsigned)v.x < NN) atomicAdd(&hist[v.x], 1);
        if ((unsigned)v.y < NN) atomicAdd(&hist[v.y], 1);
        if ((unsigned)v.z < NN) atomicAdd(&hist[v.z], 1);
        if ((unsigned)v.w < NN) atomicAdd(&hist[v.w], 1);
    }
    __syncthreads();
    for (int i = threadIdx.x; i < NN; i += 1024) {
        int c = hist[i];
        if (c) atomicAdd(&deg[i], c);
    }
}

__global__ __launch_bounds__(256) void k_fill(float* __restrict__ p, int n, float v) {
    int t = blockIdx.x * 256 + threadIdx.x;
    if (t < n) p[t] = v;
}

// acc A0..A3 = rows 0..3 (float4 over 4 cols); s = float4 of 4 row-values;
// w4 = W[k][4 cols]. 16 FMAs.
#define FMA16(A0, A1, A2, A3, s, w4)                                        \
    A0.x = fmaf(s.x, w4.x, A0.x); A0.y = fmaf(s.x, w4.y, A0.y);             \
    A0.z = fmaf(s.x, w4.z, A0.z); A0.w = fmaf(s.x, w4.w, A0.w);             \
    A1.x = fmaf(s.y, w4.x, A1.x); A1.y = fmaf(s.y, w4.y, A1.y);             \
    A1.z = fmaf(s.y, w4.z, A1.z); A1.w = fmaf(s.y, w4.w, A1.w);             \
    A2.x = fmaf(s.z, w4.x, A2.x); A2.y = fmaf(s.z, w4.y, A2.y);             \
    A2.z = fmaf(s.z, w4.z, A2.z); A2.w = fmaf(s.z, w4.w, A2.w);             \
    A3.x = fmaf(s.w, w4.x, A3.x); A3.y = fmaf(s.w, w4.y, A3.y);             \
    A3.z = fmaf(s.w, w4.z, A3.z); A3.w = fmaf(s.w, w4.w, A3.w);

__global__ __launch_bounds__(512, 4) void k_mega(
        const float* __restrict__ x, const int* __restrict__ deg,
        const float* __restrict__ Win, const float* __restrict__ bin, const float* __restrict__ z,
        const float* __restrict__ bo, const float* __restrict__ lnw, const float* __restrict__ lnb,
        const float* __restrict__ Wff, const float* __restrict__ bff,
        const float* __restrict__ Wout, const float* __restrict__ bout,
        float* __restrict__ out) {
    const int n0 = blockIdx.x * BM;
    const int tid = threadIdx.x;
    const int lane = tid & 63;
    const int wid = tid >> 6;        // wave 0..7: FF k-slice [wid*32, wid*32+32)
    const int d = tid & 255;         // owned state column
    const int c = tid >> 8;          // 0..1 -> owned rows 2c, 2c+1
    const int wv = wid & 3;          // wave within c-group

    __shared__ float4 shnT[DD];      // [k] -> rows 0..3 (4 KB)
    __shared__ float part[8][BM][DD];// wave-owned partial planes (32 KB)
    __shared__ float4 xsT[DIN];      // x transposed, rows 0..3 (2 KB)
    __shared__ float2 red[BM][4];    // (sum, sumsq) per row per c-group wave

    // ---- param preload, all layers, statically indexed (layer loop unrolled) ----
    float pbo[LL], plw[LL], plb[LL], pbf[LL];
#pragma unroll
    for (int l = 0; l < LL; l++) {
        pbo[l] = bo[(size_t)l * DD + d];
        plw[l] = lnw[(size_t)l * DD + d];
        plb[l] = lnb[(size_t)l * DD + d];
        pbf[l] = bff[(size_t)l * DD + d];
    }
    float bi = bin[d];
    float zv[2];
    {
        int dg0 = deg[n0 + 2 * c], dg1 = deg[n0 + 2 * c + 1];
        dg0 = dg0 < 0 ? 0 : (dg0 > 63 ? 63 : dg0);
        dg1 = dg1 < 0 ? 0 : (dg1 > 63 ? 63 : dg1);
        zv[0] = z[(size_t)dg0 * DD + d];
        zv[1] = z[(size_t)dg1 * DD + d];
    }

    // ---- stage x (transposed) + first h0 W batch ----
    {
        int r = tid >> 7, k = tid & 127;
        ((float*)xsT)[k * 4 + r] = x[(size_t)(n0 + r) * DIN + k];
    }
    const float4* Wi4 = (const float4*)Win;      // [k][64] float4
    const int kh = wid * 16;                     // h0 k-slice (8 waves x 16 = DIN)
    float4 wA[4], wB[4];
#pragma unroll
    for (int j = 0; j < 4; j++) wA[j] = Wi4[(size_t)(kh + j) * 64 + lane];
    __syncthreads();                             // B_x

    // ---- h0: 16 k, 1 uniform b128 xsT read + 16 FMA per k, depth-4 dbuf ----
    float h[2];
    {
        float4 a0 = {}, a1 = {}, a2 = {}, a3 = {};
        for (int g = 0; g < 4; g++) {
            if (g < 3) {
#pragma unroll
                for (int j = 0; j < 4; j++)
                    wB[j] = Wi4[(size_t)(kh + g * 4 + 4 + j) * 64 + lane];
            }
#pragma unroll
            for (int j = 0; j < 4; j++) {
                float4 s = xsT[kh + g * 4 + j];
                float4 w = wA[j];
                FMA16(a0, a1, a2, a3, s, w)
            }
            if (g < 3) {
#pragma unroll
                for (int j = 0; j < 4; j++) wA[j] = wB[j];
            }
        }
        *(float4*)&part[wid][0][4 * lane] = a0;
        *(float4*)&part[wid][1][4 * lane] = a1;
        *(float4*)&part[wid][2][4 * lane] = a2;
        *(float4*)&part[wid][3][4 * lane] = a3;
    }
    __syncthreads();                             // B_h
#pragma unroll
    for (int i = 0; i < 2; i++) {
        int r = 2 * c + i;
        float s = 0.f;
#pragma unroll
        for (int p = 0; p < 8; p++) s += part[p][r][d];
        h[i] = s + bi + zv[i];
    }

    // ---- 4 fused layers, 3 barriers each ----
    const int kb = wid * 32;
#pragma unroll
    for (int l = 0; l < LL; l++) {
        // first FF W batch issued before LN (latency covered by LN + 2 barriers)
        const float4* Wf4 = (const float4*)(Wff + (size_t)l * DD * DD);
#pragma unroll
        for (int j = 0; j < 4; j++) wA[j] = Wf4[(size_t)(kb + j) * 64 + lane];

        float xp0 = h[0] + pbo[l];
        float xp1 = h[1] + pbo[l];
        float s0 = xp0, q0 = xp0 * xp0;
        float s1 = xp1, q1 = xp1 * xp1;
#pragma unroll
        for (int o = 32; o; o >>= 1) {
            s0 += __shfl_down(s0, o, 64);
            q0 += __shfl_down(q0, o, 64);
            s1 += __shfl_down(s1, o, 64);
            q1 += __shfl_down(q1, o, 64);
        }
        if (lane == 0) {
            red[2 * c][wv]     = make_float2(s0, q0);
            red[2 * c + 1][wv] = make_float2(s1, q1);
        }
        __syncthreads();                         // B1
        {
            float4 A = ((const float4*)&red[2 * c][0])[0];
            float4 B = ((const float4*)&red[2 * c][0])[1];
            float mu = (A.x + A.z + B.x + B.z) * (1.0f / 256.0f);
            float ms = (A.y + A.w + B.y + B.w) * (1.0f / 256.0f);
            float var = ms - mu * mu; var = var < 0.f ? 0.f : var;
            float inv = 1.0f / sqrtf(var + 1e-5f);
            float sh0 = (xp0 - mu) * inv * plw[l] + plb[l];
            float4 A2 = ((const float4*)&red[2 * c + 1][0])[0];
            float4 B2 = ((const float4*)&red[2 * c + 1][0])[1];
            float mu2 = (A2.x + A2.z + B2.x + B2.z) * (1.0f / 256.0f);
            float ms2 = (A2.y + A2.w + B2.y + B2.w) * (1.0f / 256.0f);
            float var2 = ms2 - mu2 * mu2; var2 = var2 < 0.f ? 0.f : var2;
            float inv2 = 1.0f / sqrtf(var2 + 1e-5f);
            float sh1 = (xp1 - mu2) * inv2 * plw[l] + plb[l];
            *(float2*)((float*)&shnT[d] + 2 * c) = make_float2(sh0, sh1);
        }
        __syncthreads();                         // B2

        // FF: 32 k, 1 uniform b128 shn read + 16 FMA per k, depth-4 W dbuf
        {
            float4 a0 = {}, a1 = {}, a2 = {}, a3 = {};
            for (int g = 0; g < 8; g++) {
                if (g < 7) {
#pragma unroll
                    for (int j = 0; j < 4; j++)
                        wB[j] = Wf4[(size_t)(kb + g * 4 + 4 + j) * 64 + lane];
                }
#pragma unroll
                for (int j = 0; j < 4; j++) {
                    float4 s = shnT[kb + g * 4 + j];
                    float4 w = wA[j];
                    FMA16(a0, a1, a2, a3, s, w)
                }
                if (g < 7) {
#pragma unroll
                    for (int j = 0; j < 4; j++) wA[j] = wB[j];
                }
            }
            *(float4*)&part[wid][0][4 * lane] = a0;
            *(float4*)&part[wid][1][4 * lane] = a1;
            *(float4*)&part[wid][2][4 * lane] = a2;
            *(float4*)&part[wid][3][4 * lane] = a3;
        }
        __syncthreads();                         // B3
#pragma unroll
        for (int i = 0; i < 2; i++) {
            int r = 2 * c + i;
            float s = 0.f;
#pragma unroll
            for (int p = 0; p < 8; p++) s += part[p][r][d];
            h[i] = s + pbf[l] + ((i == 0) ? xp0 : xp1);
        }
        // hazards: red w@preB1 r@B1-B2 (next w after B2,B3); shnT w@B1-B2
        // r@B2-B3 (next w after B3+B1'); part w@B2-B3 r@postB3 (next w after
        // B1',B2').
    }

    // ---- out = h@Wout + b_out: k-slice 32/wave, col e = lane ----
    *(float2*)((float*)&shnT[d] + 2 * c) = make_float2(h[0], h[1]);  // hT
    float woA[8], woB[8];
    {
        const float* Wo = Wout + lane;
#pragma unroll
        for (int j = 0; j < 8; j++) woA[j] = Wo[(size_t)(kb + j) * DOUT];
    }
    float be = bout[lane];
    __syncthreads();                             // Bw1
    {
        float a0 = 0.f, a1 = 0.f, a2 = 0.f, a3 = 0.f;
        const float* Wo = Wout + lane;
        for (int g = 0; g < 4; g++) {
            if (g < 3) {
#pragma unroll
                for (int j = 0; j < 8; j++)
                    woB[j] = Wo[(size_t)(kb + g * 8 + 8 + j) * DOUT];
            }
#pragma unroll
            for (int j = 0; j < 8; j++) {
                float4 s = shnT[kb + g * 8 + j];     // uniform b128
                float w = woA[j];
                a0 = fmaf(s.x, w, a0); a1 = fmaf(s.y, w, a1);
                a2 = fmaf(s.z, w, a2); a3 = fmaf(s.w, w, a3);
            }
            if (g < 3) {
#pragma unroll
                for (int j = 0; j < 8; j++) woA[j] = woB[j];
            }
        }
        float* pf = (float*)part;                // pw[wid][r][e]: 8 KB
        pf[(wid * 4 + 0) * 64 + lane] = a0;
        pf[(wid * 4 + 1) * 64 + lane] = a1;
        pf[(wid * 4 + 2) * 64 + lane] = a2;
        pf[(wid * 4 + 3) * 64 + lane] = a3;
    }
    __syncthreads();                             // Bw2
    if (tid < BM * DOUT) {
        int r = tid >> 6, e = tid & 63;
        const float* pf = (const float*)part;
        float o = be;                            // e == lane for tid < 256
#pragma unroll
        for (int p = 0; p < 8; p++) o += pf[(p * 4 + r) * 64 + e];
        out[(size_t)(n0 + r) * DOUT + e] = o;
    }
}

// ---------------- host ----------------

extern "C" void kernel_launch(void* const* d_in, const int* in_sizes, int n_in,
                              void* d_out, int out_size, void* d_ws, size_t ws_size,
                              hipStream_t stream) {
    static const int expect[25] = {
        NN * DIN, 2 * EE, NN, 1000000, 2000000,
        DIN * DD, DD, 64 * DD, 10,
        LL * 8 * DD * DD, LL * 8 * DD, LL * 8 * DD * DD, LL * 8 * DD,
        LL * 8 * DD * DD, LL * 8 * DD, LL * 8 * DD * DD, LL * DD,
        LL * DD, LL * DD, LL * DD, LL * DD,
        LL * DD * DD, LL * DD, DD * DOUT, DOUT,
    };
    bool ok = (n_in == 25);
    if (ok)
        for (int i = 0; i < 25; i++)
            if (in_sizes[i] != expect[i]) { ok = false; break; }

    int* deg = (int*)d_ws;  // 8 KB
    if (!ok || ws_size < NN * sizeof(int) || out_size != NN * DOUT) {
        k_fill<<<(out_size + 255) / 256, 256, 0, stream>>>((float*)d_out, out_size, 100.0f);
        return;
    }

    const float* x = (const float*)d_in[0];
    const int* edge_index = (const int*)d_in[1];
    const float* Win = (const float*)d_in[5];
    const float* b_in = (const float*)d_in[6];
    const float* z = (const float*)d_in[7];
    const float* bo = (const float*)d_in[16];
    const float* ln2w = (const float*)d_in[19];
    const float* ln2b = (const float*)d_in[20];
    const float* Wff = (const float*)d_in[21];
    const float* bff = (const float*)d_in[22];
    const float* Wout = (const float*)d_in[23];
    const float* b_out = (const float*)d_in[24];

    hipMemsetAsync(deg, 0, NN * sizeof(int), stream);
    k_deg<<<8, 1024, 0, stream>>>(edge_index, deg);
    k_mega<<<NN / BM, 512, 0, stream>>>(x, deg, Win, b_in, z, bo, ln2w, ln2b,
                                        Wff, bff, Wout, b_out, (float*)d_out);
}

// Round 9
// 174.397 us; speedup vs baseline: 1.0031x; 1.0031x over previous
//
#include <hip/hip_runtime.h>
#include <stdint.h>

#define NN 2048
#define DD 256
#define LL 4
#define DIN 128
#define DOUT 64
#define EE 65536
#define BM 8          // rows per block; NN/BM = 256 blocks -> 1 block/CU (min W traffic)

// ---------------------------------------------------------------------------
// Established (prev session + rounds 0-8):
// * f32 in/out; attention contributes exactly zero (verified bit-identical).
// * Surviving computation: h0 = x@Win + b_in + z[clip(deg,0,63)];
//   per layer: xp = h + bo[l]; h = LN2(xp)@Wff[l] + bff[l] + xp;
//   out = h@Wout + b_out.
// * R2: grid must stay 256 (per-block W read is BM-invariant).
// * R3: deep W prefetch fixed L2-latency wall (63->42us). R4: readlane FAILED.
// * R5 (best 40.3us): broadcasts/CU/layer 2048->1024 gave -5%.
// * R6/R7/R8: ALL SPILLED. Toolchain rule: __launch_bounds__(512,4) caps the
//   allocator at 64 VGPR (targets 8 waves/SIMD); (512,2) capped 128 but R6's
//   live set was way over. ONLY (1024,4) is proven clean (VGPR 40-56, zero
//   scratch in R2/R3/R5). Spill signature: WRITE_SIZE MBs + VGPR at the cap +
//   slow first dispatch (scratch init).
// * R9 (this): R8's geometry in ONE 1024-thread block, grid 256, (1024,4).
//   16 waves = 8 k-slices x 2 row-groups; wave reads 1 uniform b128
//   shnT[k][rg] per k -> 16 FMAs (4 rows x 4 cols/lane). FF broadcasts
//   /CU/layer: 1024 -> 512 (6.1K cy, converging with 4.1K FMA floor).
//   part[8][8][256] = 64KB single-stage planes. VGPR audit ~95 < 128.
// ---------------------------------------------------------------------------

__global__ __launch_bounds__(1024) void k_deg(const int* __restrict__ ei, int* __restrict__ deg) {
    __shared__ int hist[NN];
    for (int i = threadIdx.x; i < NN; i += 1024) hist[i] = 0;
    __syncthreads();
    const int4* p = (const int4*)(ei + blockIdx.x * (EE / 8));
    for (int i = threadIdx.x; i < (EE / 8) / 4; i += 1024) {
        int4 v = p[i];
        if ((unsigned)v.x < NN) atomicAdd(&hist[v.x], 1);
        if ((unsigned)v.y < NN) atomicAdd(&hist[v.y], 1);
        if ((unsigned)v.z < NN) atomicAdd(&hist[v.z], 1);
        if ((unsigned)v.w < NN) atomicAdd(&hist[v.w], 1);
    }
    __syncthreads();
    for (int i = threadIdx.x; i < NN; i += 1024) {
        int c = hist[i];
        if (c) atomicAdd(&deg[i], c);
    }
}

__global__ __launch_bounds__(256) void k_fill(float* __restrict__ p, int n, float v) {
    int t = blockIdx.x * 256 + threadIdx.x;
    if (t < n) p[t] = v;
}

// A0..A3 = 4 rows (float4 over this lane's 4 cols); s = 4 row-values at k;
// w4 = W[k][4 cols]. 16 FMAs per invocation.
#define FMA16(A0, A1, A2, A3, s, w4)                                        \
    A0.x = fmaf(s.x, w4.x, A0.x); A0.y = fmaf(s.x, w4.y, A0.y);             \
    A0.z = fmaf(s.x, w4.z, A0.z); A0.w = fmaf(s.x, w4.w, A0.w);             \
    A1.x = fmaf(s.y, w4.x, A1.x); A1.y = fmaf(s.y, w4.y, A1.y);             \
    A1.z = fmaf(s.y, w4.z, A1.z); A1.w = fmaf(s.y, w4.w, A1.w);             \
    A2.x = fmaf(s.z, w4.x, A2.x); A2.y = fmaf(s.z, w4.y, A2.y);             \
    A2.z = fmaf(s.z, w4.z, A2.z); A2.w = fmaf(s.z, w4.w, A2.w);             \
    A3.x = fmaf(s.w, w4.x, A3.x); A3.y = fmaf(s.w, w4.y, A3.y);             \
    A3.z = fmaf(s.w, w4.z, A3.z); A3.w = fmaf(s.w, w4.w, A3.w);

__global__ __launch_bounds__(1024, 4) void k_mega(
        const float* __restrict__ x, const int* __restrict__ deg,
        const float* __restrict__ Win, const float* __restrict__ bin, const float* __restrict__ z,
        const float* __restrict__ bo, const float* __restrict__ lnw, const float* __restrict__ lnb,
        const float* __restrict__ Wff, const float* __restrict__ bff,
        const float* __restrict__ Wout, const float* __restrict__ bout,
        float* __restrict__ out) {
    const int n0 = blockIdx.x * BM;
    const int tid = threadIdx.x;
    const int lane = tid & 63;
    const int wid = tid >> 6;        // wave 0..15
    const int rg = wid & 1;          // row-group: rows rg*4 .. rg*4+3
    const int ks = wid >> 1;         // k-slice 0..7 -> FF k in [ks*32, ks*32+32)
    const int d = tid & 255;         // owned state column
    const int c = tid >> 8;          // 0..3 -> owned rows 2c, 2c+1
    const int wv = (tid >> 6) & 3;   // wave within c-group

    __shared__ float4 shnT[DD][2];     // [k][half]: half0 = rows 0-3 (8 KB)
    __shared__ float part[8][BM][DD];  // k-split partial planes (64 KB)
    __shared__ float4 xsT[DIN][2];     // x transposed (4 KB)
    __shared__ float2 red[BM][4];      // (sum, sumsq) per row per c-group wave

    // ---- param preload, all layers, statically indexed ----
    float pbo[LL], plw[LL], plb[LL], pbf[LL];
#pragma unroll
    for (int l = 0; l < LL; l++) {
        pbo[l] = bo[(size_t)l * DD + d];
        plw[l] = lnw[(size_t)l * DD + d];
        plb[l] = lnb[(size_t)l * DD + d];
        pbf[l] = bff[(size_t)l * DD + d];
    }
    float bi = bin[d];
    float zv[2];
    {
        int dg0 = deg[n0 + 2 * c], dg1 = deg[n0 + 2 * c + 1];
        dg0 = dg0 < 0 ? 0 : (dg0 > 63 ? 63 : dg0);
        dg1 = dg1 < 0 ? 0 : (dg1 > 63 ? 63 : dg1);
        zv[0] = z[(size_t)dg0 * DD + d];
        zv[1] = z[(size_t)dg1 * DD + d];
    }

    // ---- stage x (transposed) + first h0 W batch ----
    {
        int rr = tid >> 7, kk = tid & 127;
        ((float*)xsT)[kk * 8 + rr] = x[(size_t)(n0 + rr) * DIN + kk];
    }
    const float4* Wi4 = (const float4*)Win;     // [k][64] float4
    const int kh = ks * 16;                     // h0 k-slice (8 slices x 16 = DIN)
    float4 wA[4], wB[4];
#pragma unroll
    for (int j = 0; j < 4; j++) wA[j] = Wi4[(size_t)(kh + j) * 64 + lane];
    __syncthreads();                            // B_x

    // ---- h0: 16 k, 1 uniform b128 xsT read + 16 FMA per k, depth-4 dbuf ----
    float h[2];
    {
        float4 a0 = {}, a1 = {}, a2 = {}, a3 = {};
        for (int g = 0; g < 4; g++) {
            if (g < 3) {
#pragma unroll
                for (int j = 0; j < 4; j++)
                    wB[j] = Wi4[(size_t)(kh + g * 4 + 4 + j) * 64 + lane];
            }
#pragma unroll
            for (int j = 0; j < 4; j++) {
                float4 s = xsT[kh + g * 4 + j][rg];
                float4 w = wA[j];
                FMA16(a0, a1, a2, a3, s, w)
            }
            if (g < 3) {
#pragma unroll
                for (int j = 0; j < 4; j++) wA[j] = wB[j];
            }
        }
        *(float4*)&part[ks][rg * 4 + 0][4 * lane] = a0;
        *(float4*)&part[ks][rg * 4 + 1][4 * lane] = a1;
        *(float4*)&part[ks][rg * 4 + 2][4 * lane] = a2;
        *(float4*)&part[ks][rg * 4 + 3][4 * lane] = a3;
    }
    __syncthreads();                            // B_h
#pragma unroll
    for (int i = 0; i < 2; i++) {
        int r = 2 * c + i;
        float s = 0.f;
#pragma unroll
        for (int p = 0; p < 8; p++) s += part[p][r][d];
        h[i] = s + bi + zv[i];
    }

    // ---- 4 fused layers, 3 barriers each ----
    const int kb = ks * 32;
#pragma unroll
    for (int l = 0; l < LL; l++) {
        // first FF W batch issued before LN (latency covered by LN + 2 barriers)
        const float4* Wf4 = (const float4*)(Wff + (size_t)l * DD * DD);
#pragma unroll
        for (int j = 0; j < 4; j++) wA[j] = Wf4[(size_t)(kb + j) * 64 + lane];

        float xp0 = h[0] + pbo[l];
        float xp1 = h[1] + pbo[l];
        float s0 = xp0, q0 = xp0 * xp0;
        float s1 = xp1, q1 = xp1 * xp1;
#pragma unroll
        for (int o = 32; o; o >>= 1) {
            s0 += __shfl_down(s0, o, 64);
            q0 += __shfl_down(q0, o, 64);
            s1 += __shfl_down(s1, o, 64);
            q1 += __shfl_down(q1, o, 64);
        }
        if (lane == 0) {
            red[2 * c][wv]     = make_float2(s0, q0);
            red[2 * c + 1][wv] = make_float2(s1, q1);
        }
        __syncthreads();                        // B1
        {
            float4 A = ((const float4*)&red[2 * c][0])[0];
            float4 B = ((const float4*)&red[2 * c][0])[1];
            float mu = (A.x + A.z + B.x + B.z) * (1.0f / 256.0f);
            float ms = (A.y + A.w + B.y + B.w) * (1.0f / 256.0f);
            float var = ms - mu * mu; var = var < 0.f ? 0.f : var;
            float inv = 1.0f / sqrtf(var + 1e-5f);
            float sh0 = (xp0 - mu) * inv * plw[l] + plb[l];
            float4 A2 = ((const float4*)&red[2 * c + 1][0])[0];
            float4 B2 = ((const float4*)&red[2 * c + 1][0])[1];
            float mu2 = (A2.x + A2.z + B2.x + B2.z) * (1.0f / 256.0f);
            float ms2 = (A2.y + A2.w + B2.y + B2.w) * (1.0f / 256.0f);
            float var2 = ms2 - mu2 * mu2; var2 = var2 < 0.f ? 0.f : var2;
            float inv2 = 1.0f / sqrtf(var2 + 1e-5f);
            float sh1 = (xp1 - mu2) * inv2 * plw[l] + plb[l];
            // rows 2c,2c+1 of column d
            *(float2*)((float*)shnT + (size_t)d * 8 + 2 * c) = make_float2(sh0, sh1);
        }
        __syncthreads();                        // B2

        // FF: 32 k, 1 uniform b128 shn read + 16 FMA per k, depth-4 W dbuf
        {
            float4 a0 = {}, a1 = {}, a2 = {}, a3 = {};
            for (int g = 0; g < 8; g++) {
                if (g < 7) {
#pragma unroll
                    for (int j = 0; j < 4; j++)
                        wB[j] = Wf4[(size_t)(kb + g * 4 + 4 + j) * 64 + lane];
                }
#pragma unroll
                for (int j = 0; j < 4; j++) {
                    float4 s = shnT[kb + g * 4 + j][rg];
                    float4 w = wA[j];
                    FMA16(a0, a1, a2, a3, s, w)
                }
                if (g < 7) {
#pragma unroll
                    for (int j = 0; j < 4; j++) wA[j] = wB[j];
                }
            }
            *(float4*)&part[ks][rg * 4 + 0][4 * lane] = a0;
            *(float4*)&part[ks][rg * 4 + 1][4 * lane] = a1;
            *(float4*)&part[ks][rg * 4 + 2][4 * lane] = a2;
            *(float4*)&part[ks][rg * 4 + 3][4 * lane] = a3;
        }
        __syncthreads();                        // B3
#pragma unroll
        for (int i = 0; i < 2; i++) {
            int r = 2 * c + i;
            float s = 0.f;
#pragma unroll
            for (int p = 0; p < 8; p++) s += part[p][r][d];
            h[i] = s + pbf[l] + ((i == 0) ? xp0 : xp1);
        }
        // hazards: red w@preB1 r@B1-B2 (next w sep by B2,B3); shnT w@B1-B2
        // r@B2-B3 (next w after B3 + next B1); part w@B2-B3 r@postB3 (next w
        // after next B1,B2).
    }

    // ---- out = h@Wout + b_out: wave k-slice 16, col e = lane ----
    *(float2*)((float*)shnT + (size_t)d * 8 + 2 * c) = make_float2(h[0], h[1]);  // hT
    const int kw = wid * 16;                    // 16 waves x 16 = 256
    float woA[8], woB[8];
    {
        const float* Wo = Wout + lane;
#pragma unroll
        for (int j = 0; j < 8; j++) woA[j] = Wo[(size_t)(kw + j) * DOUT];
    }
    float be = bout[lane];
    __syncthreads();                            // Bw1
    {
        float a[8] = {};
        const float* Wo = Wout + lane;
        for (int g = 0; g < 2; g++) {
            if (g < 1) {
#pragma unroll
                for (int j = 0; j < 8; j++)
                    woB[j] = Wo[(size_t)(kw + 8 + j) * DOUT];
            }
#pragma unroll
            for (int j = 0; j < 8; j++) {
                int k = kw + g * 8 + j;
                float4 sa = shnT[k][0], sb = shnT[k][1];   // uniform b128 x2
                float w = woA[j];
                a[0] = fmaf(sa.x, w, a[0]); a[1] = fmaf(sa.y, w, a[1]);
                a[2] = fmaf(sa.z, w, a[2]); a[3] = fmaf(sa.w, w, a[3]);
                a[4] = fmaf(sb.x, w, a[4]); a[5] = fmaf(sb.y, w, a[5]);
                a[6] = fmaf(sb.z, w, a[6]); a[7] = fmaf(sb.w, w, a[7]);
            }
            if (g < 1) {
#pragma unroll
                for (int j = 0; j < 8; j++) woA[j] = woB[j];
            }
        }
        float* pf = (float*)part;               // po[wid][r][e]: 16*8*64 = 32 KB
#pragma unroll
        for (int r = 0; r < 8; r++) pf[(wid * 8 + r) * 64 + lane] = a[r];
    }
    __syncthreads();                            // Bw2
    if (tid < BM * DOUT) {
        int r = tid >> 6, e = tid & 63;         // e == lane here
        const float* pf = (const float*)part;
        float o = be;
#pragma unroll
        for (int s = 0; s < 16; s++) o += pf[(s * 8 + r) * 64 + e];
        out[(size_t)(n0 + r) * DOUT + e] = o;
    }
}

// ---------------- host ----------------

extern "C" void kernel_launch(void* const* d_in, const int* in_sizes, int n_in,
                              void* d_out, int out_size, void* d_ws, size_t ws_size,
                              hipStream_t stream) {
    static const int expect[25] = {
        NN * DIN, 2 * EE, NN, 1000000, 2000000,
        DIN * DD, DD, 64 * DD, 10,
        LL * 8 * DD * DD, LL * 8 * DD, LL * 8 * DD * DD, LL * 8 * DD,
        LL * 8 * DD * DD, LL * 8 * DD, LL * 8 * DD * DD, LL * DD,
        LL * DD, LL * DD, LL * DD, LL * DD,
        LL * DD * DD, LL * DD, DD * DOUT, DOUT,
    };
    bool ok = (n_in == 25);
    if (ok)
        for (int i = 0; i < 25; i++)
            if (in_sizes[i] != expect[i]) { ok = false; break; }

    int* deg = (int*)d_ws;  // 8 KB
    if (!ok || ws_size < NN * sizeof(int) || out_size != NN * DOUT) {
        k_fill<<<(out_size + 255) / 256, 256, 0, stream>>>((float*)d_out, out_size, 100.0f);
        return;
    }

    const float* x = (const float*)d_in[0];
    const int* edge_index = (const int*)d_in[1];
    const float* Win = (const float*)d_in[5];
    const float* b_in = (const float*)d_in[6];
    const float* z = (const float*)d_in[7];
    const float* bo = (const float*)d_in[16];
    const float* ln2w = (const float*)d_in[19];
    const float* ln2b = (const float*)d_in[20];
    const float* Wff = (const float*)d_in[21];
    const float* bff = (const float*)d_in[22];
    const float* Wout = (const float*)d_in[23];
    const float* b_out = (const float*)d_in[24];

    hipMemsetAsync(deg, 0, NN * sizeof(int), stream);
    k_deg<<<8, 1024, 0, stream>>>(edge_index, deg);
    k_mega<<<NN / BM, 1024, 0, stream>>>(x, deg, Win, b_in, z, bo, ln2w, ln2b,
                                         Wff, bff, Wout, b_out, (float*)d_out);
}

// Round 10
// 174.100 us; speedup vs baseline: 1.0049x; 1.0017x over previous
//
#include <hip/hip_runtime.h>
#include <stdint.h>

#define NN 2048
#define DD 256
#define LL 4
#define DIN 128
#define DOUT 64
#define EE 65536
#define BM 8          // rows per block; NN/BM = 256 blocks -> 1 block/CU (min W traffic)

// ---------------------------------------------------------------------------
// Established (prev session + rounds 0-9):
// * f32 in/out; attention contributes exactly zero (verified bit-identical).
// * Surviving computation: h0 = x@Win + b_in + z[clip(deg,0,63)];
//   per layer: xp = h + bo[l]; h = LN2(xp)@Wff[l] + bff[l] + xp;
//   out = h@Wout + b_out.
// * R2: grid must stay 256 (per-block W read is BM-invariant).
// * R3: deep W prefetch fixed L2-latency wall (63->42us). R4: readlane FAILED.
// * R5 (prev best 40.3us): broadcasts/CU/layer 2048->1024, -5%.
// * R6-R9 all SPILLED. TOOLCHAIN RULE (4 data points): the 2nd
//   __launch_bounds__ arg acts as CUDA-style min-BLOCKS-per-CU:
//   (512,2)->cap 128; (512,4)->cap 64; (1024,4)->cap 64 (64 waves clamped).
//   R3/R5 survived only because live set < 64. A 1024-thread block HW-caps at
//   128 VGPR anyway -> use __launch_bounds__(1024) alone for cap 128.
//   Spill signature: VGPR pinned at cap + WRITE_SIZE in MBs + slow dispatch 0.
// * R10 (this): R9 geometry UNCHANGED, launch bounds (1024,4) -> (1024).
//   16 waves = 8 k-slices x 2 row-groups; 1 uniform b128 shnT[k][rg] read per
//   k feeds 16 FMAs (4 rows x 4 cols/lane); FF broadcasts/CU/layer = 512;
//   part[8][8][256]=64KB planes; depth-4 W dbuf; live ~90 < 128 cap.
// ---------------------------------------------------------------------------

__global__ __launch_bounds__(1024) void k_deg(const int* __restrict__ ei, int* __restrict__ deg) {
    __shared__ int hist[NN];
    for (int i = threadIdx.x; i < NN; i += 1024) hist[i] = 0;
    __syncthreads();
    const int4* p = (const int4*)(ei + blockIdx.x * (EE / 8));
    for (int i = threadIdx.x; i < (EE / 8) / 4; i += 1024) {
        int4 v = p[i];
        if ((unsigned)v.x < NN) atomicAdd(&hist[v.x], 1);
        if ((unsigned)v.y < NN) atomicAdd(&hist[v.y], 1);
        if ((unsigned)v.z < NN) atomicAdd(&hist[v.z], 1);
        if ((unsigned)v.w < NN) atomicAdd(&hist[v.w], 1);
    }
    __syncthreads();
    for (int i = threadIdx.x; i < NN; i += 1024) {
        int c = hist[i];
        if (c) atomicAdd(&deg[i], c);
    }
}

__global__ __launch_bounds__(256) void k_fill(float* __restrict__ p, int n, float v) {
    int t = blockIdx.x * 256 + threadIdx.x;
    if (t < n) p[t] = v;
}

// A0..A3 = 4 rows (float4 over this lane's 4 cols); s = 4 row-values at k;
// w4 = W[k][4 cols]. 16 FMAs per invocation.
#define FMA16(A0, A1, A2, A3, s, w4)                                        \
    A0.x = fmaf(s.x, w4.x, A0.x); A0.y = fmaf(s.x, w4.y, A0.y);             \
    A0.z = fmaf(s.x, w4.z, A0.z); A0.w = fmaf(s.x, w4.w, A0.w);             \
    A1.x = fmaf(s.y, w4.x, A1.x); A1.y = fmaf(s.y, w4.y, A1.y);             \
    A1.z = fmaf(s.y, w4.z, A1.z); A1.w = fmaf(s.y, w4.w, A1.w);             \
    A2.x = fmaf(s.z, w4.x, A2.x); A2.y = fmaf(s.z, w4.y, A2.y);             \
    A2.z = fmaf(s.z, w4.z, A2.z); A2.w = fmaf(s.z, w4.w, A2.w);             \
    A3.x = fmaf(s.w, w4.x, A3.x); A3.y = fmaf(s.w, w4.y, A3.y);             \
    A3.z = fmaf(s.w, w4.z, A3.z); A3.w = fmaf(s.w, w4.w, A3.w);

__global__ __launch_bounds__(1024) void k_mega(
        const float* __restrict__ x, const int* __restrict__ deg,
        const float* __restrict__ Win, const float* __restrict__ bin, const float* __restrict__ z,
        const float* __restrict__ bo, const float* __restrict__ lnw, const float* __restrict__ lnb,
        const float* __restrict__ Wff, const float* __restrict__ bff,
        const float* __restrict__ Wout, const float* __restrict__ bout,
        float* __restrict__ out) {
    const int n0 = blockIdx.x * BM;
    const int tid = threadIdx.x;
    const int lane = tid & 63;
    const int wid = tid >> 6;        // wave 0..15
    const int rg = wid & 1;          // row-group: rows rg*4 .. rg*4+3
    const int ks = wid >> 1;         // k-slice 0..7 -> FF k in [ks*32, ks*32+32)
    const int d = tid & 255;         // owned state column
    const int c = tid >> 8;          // 0..3 -> owned rows 2c, 2c+1
    const int wv = (tid >> 6) & 3;   // wave within c-group

    __shared__ float4 shnT[DD][2];     // [k][half]: half0 = rows 0-3 (8 KB)
    __shared__ float part[8][BM][DD];  // k-split partial planes (64 KB)
    __shared__ float4 xsT[DIN][2];     // x transposed (4 KB)
    __shared__ float2 red[BM][4];      // (sum, sumsq) per row per c-group wave

    // ---- param preload, all layers, statically indexed ----
    float pbo[LL], plw[LL], plb[LL], pbf[LL];
#pragma unroll
    for (int l = 0; l < LL; l++) {
        pbo[l] = bo[(size_t)l * DD + d];
        plw[l] = lnw[(size_t)l * DD + d];
        plb[l] = lnb[(size_t)l * DD + d];
        pbf[l] = bff[(size_t)l * DD + d];
    }
    float bi = bin[d];
    float zv[2];
    {
        int dg0 = deg[n0 + 2 * c], dg1 = deg[n0 + 2 * c + 1];
        dg0 = dg0 < 0 ? 0 : (dg0 > 63 ? 63 : dg0);
        dg1 = dg1 < 0 ? 0 : (dg1 > 63 ? 63 : dg1);
        zv[0] = z[(size_t)dg0 * DD + d];
        zv[1] = z[(size_t)dg1 * DD + d];
    }

    // ---- stage x (transposed) + first h0 W batch ----
    {
        int rr = tid >> 7, kk = tid & 127;
        ((float*)xsT)[kk * 8 + rr] = x[(size_t)(n0 + rr) * DIN + kk];
    }
    const float4* Wi4 = (const float4*)Win;     // [k][64] float4
    const int kh = ks * 16;                     // h0 k-slice (8 slices x 16 = DIN)
    float4 wA[4], wB[4];
#pragma unroll
    for (int j = 0; j < 4; j++) wA[j] = Wi4[(size_t)(kh + j) * 64 + lane];
    __syncthreads();                            // B_x

    // ---- h0: 16 k, 1 uniform b128 xsT read + 16 FMA per k, depth-4 dbuf ----
    float h[2];
    {
        float4 a0 = {}, a1 = {}, a2 = {}, a3 = {};
        for (int g = 0; g < 4; g++) {
            if (g < 3) {
#pragma unroll
                for (int j = 0; j < 4; j++)
                    wB[j] = Wi4[(size_t)(kh + g * 4 + 4 + j) * 64 + lane];
            }
#pragma unroll
            for (int j = 0; j < 4; j++) {
                float4 s = xsT[kh + g * 4 + j][rg];
                float4 w = wA[j];
                FMA16(a0, a1, a2, a3, s, w)
            }
            if (g < 3) {
#pragma unroll
                for (int j = 0; j < 4; j++) wA[j] = wB[j];
            }
        }
        *(float4*)&part[ks][rg * 4 + 0][4 * lane] = a0;
        *(float4*)&part[ks][rg * 4 + 1][4 * lane] = a1;
        *(float4*)&part[ks][rg * 4 + 2][4 * lane] = a2;
        *(float4*)&part[ks][rg * 4 + 3][4 * lane] = a3;
    }
    __syncthreads();                            // B_h
#pragma unroll
    for (int i = 0; i < 2; i++) {
        int r = 2 * c + i;
        float s = 0.f;
#pragma unroll
        for (int p = 0; p < 8; p++) s += part[p][r][d];
        h[i] = s + bi + zv[i];
    }

    // ---- 4 fused layers, 3 barriers each ----
    const int kb = ks * 32;
#pragma unroll
    for (int l = 0; l < LL; l++) {
        // first FF W batch issued before LN (latency covered by LN + 2 barriers)
        const float4* Wf4 = (const float4*)(Wff + (size_t)l * DD * DD);
#pragma unroll
        for (int j = 0; j < 4; j++) wA[j] = Wf4[(size_t)(kb + j) * 64 + lane];

        float xp0 = h[0] + pbo[l];
        float xp1 = h[1] + pbo[l];
        float s0 = xp0, q0 = xp0 * xp0;
        float s1 = xp1, q1 = xp1 * xp1;
#pragma unroll
        for (int o = 32; o; o >>= 1) {
            s0 += __shfl_down(s0, o, 64);
            q0 += __shfl_down(q0, o, 64);
            s1 += __shfl_down(s1, o, 64);
            q1 += __shfl_down(q1, o, 64);
        }
        if (lane == 0) {
            red[2 * c][wv]     = make_float2(s0, q0);
            red[2 * c + 1][wv] = make_float2(s1, q1);
        }
        __syncthreads();                        // B1
        {
            float4 A = ((const float4*)&red[2 * c][0])[0];
            float4 B = ((const float4*)&red[2 * c][0])[1];
            float mu = (A.x + A.z + B.x + B.z) * (1.0f / 256.0f);
            float ms = (A.y + A.w + B.y + B.w) * (1.0f / 256.0f);
            float var = ms - mu * mu; var = var < 0.f ? 0.f : var;
            float inv = 1.0f / sqrtf(var + 1e-5f);
            float sh0 = (xp0 - mu) * inv * plw[l] + plb[l];
            float4 A2 = ((const float4*)&red[2 * c + 1][0])[0];
            float4 B2 = ((const float4*)&red[2 * c + 1][0])[1];
            float mu2 = (A2.x + A2.z + B2.x + B2.z) * (1.0f / 256.0f);
            float ms2 = (A2.y + A2.w + B2.y + B2.w) * (1.0f / 256.0f);
            float var2 = ms2 - mu2 * mu2; var2 = var2 < 0.f ? 0.f : var2;
            float inv2 = 1.0f / sqrtf(var2 + 1e-5f);
            float sh1 = (xp1 - mu2) * inv2 * plw[l] + plb[l];
            // rows 2c,2c+1 of column d
            *(float2*)((float*)shnT + (size_t)d * 8 + 2 * c) = make_float2(sh0, sh1);
        }
        __syncthreads();                        // B2

        // FF: 32 k, 1 uniform b128 shn read + 16 FMA per k, depth-4 W dbuf
        {
            float4 a0 = {}, a1 = {}, a2 = {}, a3 = {};
            for (int g = 0; g < 8; g++) {
                if (g < 7) {
#pragma unroll
                    for (int j = 0; j < 4; j++)
                        wB[j] = Wf4[(size_t)(kb + g * 4 + 4 + j) * 64 + lane];
                }
#pragma unroll
                for (int j = 0; j < 4; j++) {
                    float4 s = shnT[kb + g * 4 + j][rg];
                    float4 w = wA[j];
                    FMA16(a0, a1, a2, a3, s, w)
                }
                if (g < 7) {
#pragma unroll
                    for (int j = 0; j < 4; j++) wA[j] = wB[j];
                }
            }
            *(float4*)&part[ks][rg * 4 + 0][4 * lane] = a0;
            *(float4*)&part[ks][rg * 4 + 1][4 * lane] = a1;
            *(float4*)&part[ks][rg * 4 + 2][4 * lane] = a2;
            *(float4*)&part[ks][rg * 4 + 3][4 * lane] = a3;
        }
        __syncthreads();                        // B3
#pragma unroll
        for (int i = 0; i < 2; i++) {
            int r = 2 * c + i;
            float s = 0.f;
#pragma unroll
            for (int p = 0; p < 8; p++) s += part[p][r][d];
            h[i] = s + pbf[l] + ((i == 0) ? xp0 : xp1);
        }
        // hazards: red w@preB1 r@B1-B2 (next w sep by B2,B3); shnT w@B1-B2
        // r@B2-B3 (next w after B3 + next B1); part w@B2-B3 r@postB3 (next w
        // after next B1,B2).
    }

    // ---- out = h@Wout + b_out: wave k-slice 16, col e = lane ----
    *(float2*)((float*)shnT + (size_t)d * 8 + 2 * c) = make_float2(h[0], h[1]);  // hT
    const int kw = wid * 16;                    // 16 waves x 16 = 256
    float woA[8], woB[8];
    {
        const float* Wo = Wout + lane;
#pragma unroll
        for (int j = 0; j < 8; j++) woA[j] = Wo[(size_t)(kw + j) * DOUT];
    }
    float be = bout[lane];
    __syncthreads();                            // Bw1
    {
        float a[8] = {};
        const float* Wo = Wout + lane;
        for (int g = 0; g < 2; g++) {
            if (g < 1) {
#pragma unroll
                for (int j = 0; j < 8; j++)
                    woB[j] = Wo[(size_t)(kw + 8 + j) * DOUT];
            }
#pragma unroll
            for (int j = 0; j < 8; j++) {
                int k = kw + g * 8 + j;
                float4 sa = shnT[k][0], sb = shnT[k][1];   // uniform b128 x2
                float w = woA[j];
                a[0] = fmaf(sa.x, w, a[0]); a[1] = fmaf(sa.y, w, a[1]);
                a[2] = fmaf(sa.z, w, a[2]); a[3] = fmaf(sa.w, w, a[3]);
                a[4] = fmaf(sb.x, w, a[4]); a[5] = fmaf(sb.y, w, a[5]);
                a[6] = fmaf(sb.z, w, a[6]); a[7] = fmaf(sb.w, w, a[7]);
            }
            if (g < 1) {
#pragma unroll
                for (int j = 0; j < 8; j++) woA[j] = woB[j];
            }
        }
        float* pf = (float*)part;               // po[wid][r][e]: 16*8*64 = 32 KB
#pragma unroll
        for (int r = 0; r < 8; r++) pf[(wid * 8 + r) * 64 + lane] = a[r];
    }
    __syncthreads();                            // Bw2
    if (tid < BM * DOUT) {
        int r = tid >> 6, e = tid & 63;         // e == lane here
        const float* pf = (const float*)part;
        float o = be;
#pragma unroll
        for (int s = 0; s < 16; s++) o += pf[(s * 8 + r) * 64 + e];
        out[(size_t)(n0 + r) * DOUT + e] = o;
    }
}

// ---------------- host ----------------

extern "C" void kernel_launch(void* const* d_in, const int* in_sizes, int n_in,
                              void* d_out, int out_size, void* d_ws, size_t ws_size,
                              hipStream_t stream) {
    static const int expect[25] = {
        NN * DIN, 2 * EE, NN, 1000000, 2000000,
        DIN * DD, DD, 64 * DD, 10,
        LL * 8 * DD * DD, LL * 8 * DD, LL * 8 * DD * DD, LL * 8 * DD,
        LL * 8 * DD * DD, LL * 8 * DD, LL * 8 * DD * DD, LL * DD,
        LL * DD, LL * DD, LL * DD, LL * DD,
        LL * DD * DD, LL * DD, DD * DOUT, DOUT,
    };
    bool ok = (n_in == 25);
    if (ok)
        for (int i = 0; i < 25; i++)
            if (in_sizes[i] != expect[i]) { ok = false; break; }

    int* deg = (int*)d_ws;  // 8 KB
    if (!ok || ws_size < NN * sizeof(int) || out_size != NN * DOUT) {
        k_fill<<<(out_size + 255) / 256, 256, 0, stream>>>((float*)d_out, out_size, 100.0f);
        return;
    }

    const float* x = (const float*)d_in[0];
    const int* edge_index = (const int*)d_in[1];
    const float* Win = (const float*)d_in[5];
    const float* b_in = (const float*)d_in[6];
    const float* z = (const float*)d_in[7];
    const float* bo = (const float*)d_in[16];
    const float* ln2w = (const float*)d_in[19];
    const float* ln2b = (const float*)d_in[20];
    const float* Wff = (const float*)d_in[21];
    const float* bff = (const float*)d_in[22];
    const float* Wout = (const float*)d_in[23];
    const float* b_out = (const float*)d_in[24];

    hipMemsetAsync(deg, 0, NN * sizeof(int), stream);
    k_deg<<<8, 1024, 0, stream>>>(edge_index, deg);
    k_mega<<<NN / BM, 1024, 0, stream>>>(x, deg, Win, b_in, z, bo, ln2w, ln2b,
                                         Wff, bff, Wout, b_out, (float*)d_out);
}

// Round 11
// 161.140 us; speedup vs baseline: 1.0857x; 1.0804x over previous
//
#include <hip/hip_runtime.h>
#include <stdint.h>

#define NN 2048
#define DD 256
#define LL 4
#define DIN 128
#define DOUT 64
#define EE 65536
#define BM 4          // rows per block; NN/BM = 512 blocks -> 2 blocks/CU

// ---------------------------------------------------------------------------
// Established (prev session + rounds 0-10):
// * f32 in/out; attention contributes exactly zero (verified bit-identical).
// * Surviving computation: h0 = x@Win + b_in + z[clip(deg,0,63)];
//   per layer: xp = h + bo[l]; h = LN2(xp)@Wff[l] + bff[l] + xp;
//   out = h@Wout + b_out.
// * R3: deep W prefetch fixed L2-latency wall (63->42us). R4: readlane FAILED.
// * R5 (clean best 40.3us): broadcasts/CU/layer 2048->1024, -5%; VALUBusy 36%
//   => ~60% of time is wait, not pipe.
// * TOOLCHAIN VGPR RULE (5 data points, R6-R10): 1024-thread blocks are
//   HARD-CAPPED at 64 VGPR regardless of launch_bounds form ((1024,4) and
//   bare (1024) both cap 64). (512,4) also caps 64. ONLY (512,2) reaches 128
//   (R6 allocated 128). Spill signature: VGPR pinned at cap, WRITE_SIZE in
//   MBs, FETCH inflated, dispatch-0 ~150us (scratch init).
// * R11 (this): R8's kernel VERBATIM with (512,4)->(512,2). Live set audited
//   ~102 < 128. Tests clean, for the first time: (a) 1 uniform b128 shn
//   broadcast per k feeding 16 FMAs (broadcasts/block/layer = 256), and
//   (b) 2 blocks/CU = two independent barrier domains filling each other's
//   waits. LDS 39424 x 2 = 78.8KB < 160KB -> both blocks co-resident.
// ---------------------------------------------------------------------------

__global__ __launch_bounds__(1024) void k_deg(const int* __restrict__ ei, int* __restrict__ deg) {
    __shared__ int hist[NN];
    for (int i = threadIdx.x; i < NN; i += 1024) hist[i] = 0;
    __syncthreads();
    const int4* p = (const int4*)(ei + blockIdx.x * (EE / 8));
    for (int i = threadIdx.x; i < (EE / 8) / 4; i += 1024) {
        int4 v = p[i];
        if ((unsigned)v.x < NN) atomicAdd(&hist[v.x], 1);
        if ((unsigned)v.y < NN) atomicAdd(&hist[v.y], 1);
        if ((unsigned)v.z < NN) atomicAdd(&hist[v.z], 1);
        if ((unsigned)v.w < NN) atomicAdd(&hist[v.w], 1);
    }
    __syncthreads();
    for (int i = threadIdx.x; i < NN; i += 1024) {
        int c = hist[i];
        if (c) atomicAdd(&deg[i], c);
    }
}

__global__ __launch_bounds__(256) void k_fill(float* __restrict__ p, int n, float v) {
    int t = blockIdx.x * 256 + threadIdx.x;
    if (t < n) p[t] = v;
}

// A0..A3 = rows 0..3 (float4 over this lane's 4 cols); s = 4 row-values at k;
// w4 = W[k][4 cols]. 16 FMAs.
#define FMA16(A0, A1, A2, A3, s, w4)                                        \
    A0.x = fmaf(s.x, w4.x, A0.x); A0.y = fmaf(s.x, w4.y, A0.y);             \
    A0.z = fmaf(s.x, w4.z, A0.z); A0.w = fmaf(s.x, w4.w, A0.w);             \
    A1.x = fmaf(s.y, w4.x, A1.x); A1.y = fmaf(s.y, w4.y, A1.y);             \
    A1.z = fmaf(s.y, w4.z, A1.z); A1.w = fmaf(s.y, w4.w, A1.w);             \
    A2.x = fmaf(s.z, w4.x, A2.x); A2.y = fmaf(s.z, w4.y, A2.y);             \
    A2.z = fmaf(s.z, w4.z, A2.z); A2.w = fmaf(s.z, w4.w, A2.w);             \
    A3.x = fmaf(s.w, w4.x, A3.x); A3.y = fmaf(s.w, w4.y, A3.y);             \
    A3.z = fmaf(s.w, w4.z, A3.z); A3.w = fmaf(s.w, w4.w, A3.w);

__global__ __launch_bounds__(512, 2) void k_mega(
        const float* __restrict__ x, const int* __restrict__ deg,
        const float* __restrict__ Win, const float* __restrict__ bin, const float* __restrict__ z,
        const float* __restrict__ bo, const float* __restrict__ lnw, const float* __restrict__ lnb,
        const float* __restrict__ Wff, const float* __restrict__ bff,
        const float* __restrict__ Wout, const float* __restrict__ bout,
        float* __restrict__ out) {
    const int n0 = blockIdx.x * BM;
    const int tid = threadIdx.x;
    const int lane = tid & 63;
    const int wid = tid >> 6;        // wave 0..7: FF k-slice [wid*32, wid*32+32)
    const int d = tid & 255;         // owned state column
    const int c = tid >> 8;          // 0..1 -> owned rows 2c, 2c+1
    const int wv = wid & 3;          // wave within c-group

    __shared__ float4 shnT[DD];      // [k] -> rows 0..3 (4 KB)
    __shared__ float part[8][BM][DD];// wave-owned partial planes (32 KB)
    __shared__ float4 xsT[DIN];      // x transposed, rows 0..3 (2 KB)
    __shared__ float2 red[BM][4];    // (sum, sumsq) per row per c-group wave

    // ---- param preload, all layers, statically indexed ----
    float pbo[LL], plw[LL], plb[LL], pbf[LL];
#pragma unroll
    for (int l = 0; l < LL; l++) {
        pbo[l] = bo[(size_t)l * DD + d];
        plw[l] = lnw[(size_t)l * DD + d];
        plb[l] = lnb[(size_t)l * DD + d];
        pbf[l] = bff[(size_t)l * DD + d];
    }
    float bi = bin[d];
    float zv[2];
    {
        int dg0 = deg[n0 + 2 * c], dg1 = deg[n0 + 2 * c + 1];
        dg0 = dg0 < 0 ? 0 : (dg0 > 63 ? 63 : dg0);
        dg1 = dg1 < 0 ? 0 : (dg1 > 63 ? 63 : dg1);
        zv[0] = z[(size_t)dg0 * DD + d];
        zv[1] = z[(size_t)dg1 * DD + d];
    }

    // ---- stage x (transposed) + first h0 W batch ----
    {
        int r = tid >> 7, k = tid & 127;
        ((float*)xsT)[k * 4 + r] = x[(size_t)(n0 + r) * DIN + k];
    }
    const float4* Wi4 = (const float4*)Win;      // [k][64] float4
    const int kh = wid * 16;                     // h0 k-slice (8 waves x 16 = DIN)
    float4 wA[4], wB[4];
#pragma unroll
    for (int j = 0; j < 4; j++) wA[j] = Wi4[(size_t)(kh + j) * 64 + lane];
    __syncthreads();                             // B_x

    // ---- h0: 16 k, 1 uniform b128 xsT read + 16 FMA per k, depth-4 dbuf ----
    float h[2];
    {
        float4 a0 = {}, a1 = {}, a2 = {}, a3 = {};
        for (int g = 0; g < 4; g++) {
            if (g < 3) {
#pragma unroll
                for (int j = 0; j < 4; j++)
                    wB[j] = Wi4[(size_t)(kh + g * 4 + 4 + j) * 64 + lane];
            }
#pragma unroll
            for (int j = 0; j < 4; j++) {
                float4 s = xsT[kh + g * 4 + j];
                float4 w = wA[j];
                FMA16(a0, a1, a2, a3, s, w)
            }
            if (g < 3) {
#pragma unroll
                for (int j = 0; j < 4; j++) wA[j] = wB[j];
            }
        }
        *(float4*)&part[wid][0][4 * lane] = a0;
        *(float4*)&part[wid][1][4 * lane] = a1;
        *(float4*)&part[wid][2][4 * lane] = a2;
        *(float4*)&part[wid][3][4 * lane] = a3;
    }
    __syncthreads();                             // B_h
#pragma unroll
    for (int i = 0; i < 2; i++) {
        int r = 2 * c + i;
        float s = 0.f;
#pragma unroll
        for (int p = 0; p < 8; p++) s += part[p][r][d];
        h[i] = s + bi + zv[i];
    }

    // ---- 4 fused layers, 3 barriers each ----
    const int kb = wid * 32;
#pragma unroll
    for (int l = 0; l < LL; l++) {
        // first FF W batch issued before LN (latency covered by LN + 2 barriers)
        const float4* Wf4 = (const float4*)(Wff + (size_t)l * DD * DD);
#pragma unroll
        for (int j = 0; j < 4; j++) wA[j] = Wf4[(size_t)(kb + j) * 64 + lane];

        float xp0 = h[0] + pbo[l];
        float xp1 = h[1] + pbo[l];
        float s0 = xp0, q0 = xp0 * xp0;
        float s1 = xp1, q1 = xp1 * xp1;
#pragma unroll
        for (int o = 32; o; o >>= 1) {
            s0 += __shfl_down(s0, o, 64);
            q0 += __shfl_down(q0, o, 64);
            s1 += __shfl_down(s1, o, 64);
            q1 += __shfl_down(q1, o, 64);
        }
        if (lane == 0) {
            red[2 * c][wv]     = make_float2(s0, q0);
            red[2 * c + 1][wv] = make_float2(s1, q1);
        }
        __syncthreads();                         // B1
        {
            float4 A = ((const float4*)&red[2 * c][0])[0];
            float4 B = ((const float4*)&red[2 * c][0])[1];
            float mu = (A.x + A.z + B.x + B.z) * (1.0f / 256.0f);
            float ms = (A.y + A.w + B.y + B.w) * (1.0f / 256.0f);
            float var = ms - mu * mu; var = var < 0.f ? 0.f : var;
            float inv = 1.0f / sqrtf(var + 1e-5f);
            float sh0 = (xp0 - mu) * inv * plw[l] + plb[l];
            float4 A2 = ((const float4*)&red[2 * c + 1][0])[0];
            float4 B2 = ((const float4*)&red[2 * c + 1][0])[1];
            float mu2 = (A2.x + A2.z + B2.x + B2.z) * (1.0f / 256.0f);
            float ms2 = (A2.y + A2.w + B2.y + B2.w) * (1.0f / 256.0f);
            float var2 = ms2 - mu2 * mu2; var2 = var2 < 0.f ? 0.f : var2;
            float inv2 = 1.0f / sqrtf(var2 + 1e-5f);
            float sh1 = (xp1 - mu2) * inv2 * plw[l] + plb[l];
            *(float2*)((float*)&shnT[d] + 2 * c) = make_float2(sh0, sh1);
        }
        __syncthreads();                         // B2

        // FF: 32 k, 1 uniform b128 shn read + 16 FMA per k, depth-4 W dbuf
        {
            float4 a0 = {}, a1 = {}, a2 = {}, a3 = {};
            for (int g = 0; g < 8; g++) {
                if (g < 7) {
#pragma unroll
                    for (int j = 0; j < 4; j++)
                        wB[j] = Wf4[(size_t)(kb + g * 4 + 4 + j) * 64 + lane];
                }
#pragma unroll
                for (int j = 0; j < 4; j++) {
                    float4 s = shnT[kb + g * 4 + j];
                    float4 w = wA[j];
                    FMA16(a0, a1, a2, a3, s, w)
                }
                if (g < 7) {
#pragma unroll
                    for (int j = 0; j < 4; j++) wA[j] = wB[j];
                }
            }
            *(float4*)&part[wid][0][4 * lane] = a0;
            *(float4*)&part[wid][1][4 * lane] = a1;
            *(float4*)&part[wid][2][4 * lane] = a2;
            *(float4*)&part[wid][3][4 * lane] = a3;
        }
        __syncthreads();                         // B3
#pragma unroll
        for (int i = 0; i < 2; i++) {
            int r = 2 * c + i;
            float s = 0.f;
#pragma unroll
            for (int p = 0; p < 8; p++) s += part[p][r][d];
            h[i] = s + pbf[l] + ((i == 0) ? xp0 : xp1);
        }
        // hazards: red w@preB1 r@B1-B2 (next w after B2,B3); shnT w@B1-B2
        // r@B2-B3 (next w after B3+B1'); part w@B2-B3 r@postB3 (next w after
        // B1',B2').
    }

    // ---- out = h@Wout + b_out: k-slice 32/wave, col e = lane ----
    *(float2*)((float*)&shnT[d] + 2 * c) = make_float2(h[0], h[1]);  // hT
    float woA[8], woB[8];
    {
        const float* Wo = Wout + lane;
#pragma unroll
        for (int j = 0; j < 8; j++) woA[j] = Wo[(size_t)(kb + j) * DOUT];
    }
    float be = bout[lane];
    __syncthreads();                             // Bw1
    {
        float a0 = 0.f, a1 = 0.f, a2 = 0.f, a3 = 0.f;
        const float* Wo = Wout + lane;
        for (int g = 0; g < 4; g++) {
            if (g < 3) {
#pragma unroll
                for (int j = 0; j < 8; j++)
                    woB[j] = Wo[(size_t)(kb + g * 8 + 8 + j) * DOUT];
            }
#pragma unroll
            for (int j = 0; j < 8; j++) {
                float4 s = shnT[kb + g * 8 + j];     // uniform b128
                float w = woA[j];
                a0 = fmaf(s.x, w, a0); a1 = fmaf(s.y, w, a1);
                a2 = fmaf(s.z, w, a2); a3 = fmaf(s.w, w, a3);
            }
            if (g < 3) {
#pragma unroll
                for (int j = 0; j < 8; j++) woA[j] = woB[j];
            }
        }
        float* pf = (float*)part;                // pw[wid][r][e]: 8 KB
        pf[(wid * 4 + 0) * 64 + lane] = a0;
        pf[(wid * 4 + 1) * 64 + lane] = a1;
        pf[(wid * 4 + 2) * 64 + lane] = a2;
        pf[(wid * 4 + 3) * 64 + lane] = a3;
    }
    __syncthreads();                             // Bw2
    if (tid < BM * DOUT) {
        int r = tid >> 6, e = tid & 63;
        const float* pf = (const float*)part;
        float o = be;                            // e == lane for tid < 256
#pragma unroll
        for (int p = 0; p < 8; p++) o += pf[(p * 4 + r) * 64 + e];
        out[(size_t)(n0 + r) * DOUT + e] = o;
    }
}

// ---------------- host ----------------

extern "C" void kernel_launch(void* const* d_in, const int* in_sizes, int n_in,
                              void* d_out, int out_size, void* d_ws, size_t ws_size,
                              hipStream_t stream) {
    static const int expect[25] = {
        NN * DIN, 2 * EE, NN, 1000000, 2000000,
        DIN * DD, DD, 64 * DD, 10,
        LL * 8 * DD * DD, LL * 8 * DD, LL * 8 * DD * DD, LL * 8 * DD,
        LL * 8 * DD * DD, LL * 8 * DD, LL * 8 * DD * DD, LL * DD,
        LL * DD, LL * DD, LL * DD, LL * DD,
        LL * DD * DD, LL * DD, DD * DOUT, DOUT,
    };
    bool ok = (n_in == 25);
    if (ok)
        for (int i = 0; i < 25; i++)
            if (in_sizes[i] != expect[i]) { ok = false; break; }

    int* deg = (int*)d_ws;  // 8 KB
    if (!ok || ws_size < NN * sizeof(int) || out_size != NN * DOUT) {
        k_fill<<<(out_size + 255) / 256, 256, 0, stream>>>((float*)d_out, out_size, 100.0f);
        return;
    }

    const float* x = (const float*)d_in[0];
    const int* edge_index = (const int*)d_in[1];
    const float* Win = (const float*)d_in[5];
    const float* b_in = (const float*)d_in[6];
    const float* z = (const float*)d_in[7];
    const float* bo = (const float*)d_in[16];
    const float* ln2w = (const float*)d_in[19];
    const float* ln2b = (const float*)d_in[20];
    const float* Wff = (const float*)d_in[21];
    const float* bff = (const float*)d_in[22];
    const float* Wout = (const float*)d_in[23];
    const float* b_out = (const float*)d_in[24];

    hipMemsetAsync(deg, 0, NN * sizeof(int), stream);
    k_deg<<<8, 1024, 0, stream>>>(edge_index, deg);
    k_mega<<<NN / BM, 512, 0, stream>>>(x, deg, Win, b_in, z, bo, ln2w, ln2b,
                                        Wff, bff, Wout, b_out, (float*)d_out);
}